// Round 1
// baseline (269.101 us; speedup 1.0000x reference)
//
#include <hip/hip_runtime.h>
#include <stdint.h>

typedef unsigned short u16;
typedef __attribute__((ext_vector_type(8))) short bf16x8;   // 8 bf16 in 4 VGPRs
typedef __attribute__((ext_vector_type(4))) float floatx4;

#define MFMA16(a, b, c) __builtin_amdgcn_mfma_f32_16x16x32_bf16(a, b, c, 0, 0, 0)

__device__ __forceinline__ u16 f2bf(float f) {
  union { float f; unsigned u; } v; v.f = f;
  unsigned r = (v.u + 0x7FFFu + ((v.u >> 16) & 1u)) >> 16;
  return (u16)r;
}

// async global->LDS, 16B per lane. LDS dest = wave-uniform base + lane*16 (HW).
__device__ __forceinline__ void glds16(void* lds, const void* g) {
  __builtin_amdgcn_global_load_lds((const __attribute__((address_space(1))) void*)g,
                                   (__attribute__((address_space(3))) void*)lds,
                                   16, 0, 0);
}

// ---------------------------------------------------------------- convert
__global__ __launch_bounds__(256) void cvt_bf16(const float* __restrict__ src,
                                                u16* __restrict__ dst, int n4) {
  int i = blockIdx.x * 256 + threadIdx.x;
  if (i >= n4) return;
  float4 f = reinterpret_cast<const float4*>(src)[i];
  ushort4 o;
  o.x = f2bf(f.x); o.y = f2bf(f.y); o.z = f2bf(f.z); o.w = f2bf(f.w);
  reinterpret_cast<ushort4*>(dst)[i] = o;
}

// ---------------------------------------------------------------- QKV GEMM
// C[m,n] = sum_k x[m,k] * W[n,k] + bias[n]   (x @ W^T + b), M=4096 N=1024 K=1024
// which=0 -> Q [B,H,S,dh], which=1 -> K [B,H,S,dh], which=2 -> V^T [B,H,dh,S]
__global__ __launch_bounds__(256, 2) void qkv_gemm(
    const u16* __restrict__ xb, const u16* __restrict__ Wb,
    const float* __restrict__ bq, const float* __restrict__ bk,
    const float* __restrict__ bv,
    u16* __restrict__ Qb, u16* __restrict__ Kb, u16* __restrict__ VTb) {
  __shared__ __attribute__((aligned(16))) u16 As[128 * 64];
  __shared__ __attribute__((aligned(16))) u16 Bs[128 * 64];

  const int tid = threadIdx.x;
  const int w = tid >> 6, lane = tid & 63;
  const int lo = lane & 15, hi = lane >> 4;
  const int which = blockIdx.z;
  const int n0 = blockIdx.x * 128, m0 = blockIdx.y * 128;

  const u16* W = Wb + (size_t)which * (1024 * 1024);
  const int wm = (w >> 1) * 64, wn = (w & 1) * 64;

  floatx4 acc[4][4];
  for (int i = 0; i < 4; ++i)
    for (int j = 0; j < 4; ++j) acc[i][j] = (floatx4)0.f;

  const int arow = lane >> 3;        // 0..7 within 8-row segment
  const int acol = (lane & 7) * 8;   // bf16 element offset within 64

  for (int kt = 0; kt < 16; ++kt) {
    const int k0 = kt * 64;
    for (int j = 0; j < 4; ++j) {
      const int seg = w * 4 + j;          // 16 segs of 8 rows
      const int row = seg * 8 + arow;
      glds16(As + seg * 512, xb + (size_t)(m0 + row) * 1024 + k0 + acol);
      glds16(Bs + seg * 512, W + (size_t)(n0 + row) * 1024 + k0 + acol);
    }
    __syncthreads();
    for (int kk = 0; kk < 2; ++kk) {
      bf16x8 af[4], bfr[4];
      for (int it = 0; it < 4; ++it)
        af[it] = *reinterpret_cast<const bf16x8*>(As + (wm + it * 16 + lo) * 64 + kk * 32 + hi * 8);
      for (int jt = 0; jt < 4; ++jt)
        bfr[jt] = *reinterpret_cast<const bf16x8*>(Bs + (wn + jt * 16 + lo) * 64 + kk * 32 + hi * 8);
      for (int it = 0; it < 4; ++it)
        for (int jt = 0; jt < 4; ++jt)
          acc[it][jt] = MFMA16(af[it], bfr[jt], acc[it][jt]);
    }
    __syncthreads();
  }

  const float* bias = (which == 0) ? bq : (which == 1) ? bk : bv;
  for (int it = 0; it < 4; ++it) {
    const int mrow = m0 + wm + it * 16 + hi * 4;  // +r ; multiple of 4, no batch straddle
    const int b = mrow >> 11;
    const int s = mrow & 2047;
    for (int jt = 0; jt < 4; ++jt) {
      const int ncol = n0 + wn + jt * 16 + lo;
      const int h = ncol >> 6, d = ncol & 63;
      const float bb = bias[ncol];
      if (which == 2) {
        ushort4 o;
        o.x = f2bf(acc[it][jt][0] + bb);
        o.y = f2bf(acc[it][jt][1] + bb);
        o.z = f2bf(acc[it][jt][2] + bb);
        o.w = f2bf(acc[it][jt][3] + bb);
        *reinterpret_cast<ushort4*>(VTb + ((size_t)(b * 16 + h) * 64 + d) * 2048 + s) = o;
      } else {
        u16* dst = ((which == 0) ? Qb : Kb) + ((size_t)(b * 16 + h) * 2048 + s) * 64 + d;
        for (int r = 0; r < 4; ++r)
          dst[(size_t)r * 64] = f2bf(acc[it][jt][r] + bb);
      }
    }
  }
}

// ---------------------------------------------------------------- attention
// Faithful buggy mask: keep score iff key > q, else -1e9 (so row S-1 -> uniform).
__global__ __launch_bounds__(256, 2) void attn(
    const u16* __restrict__ Qb, const u16* __restrict__ Kb,
    const u16* __restrict__ VTb, float* __restrict__ out) {
  __shared__ __attribute__((aligned(16))) u16 Ks[64 * 64];
  __shared__ __attribute__((aligned(16))) u16 Vs[64 * 64];
  __shared__ __attribute__((aligned(16))) u16 Ps[4][16 * 64];

  const int qt = blockIdx.x, bh = blockIdx.y;
  const int tid = threadIdx.x, w = tid >> 6, lane = tid & 63;
  const int lo = lane & 15, hi = lane >> 4;

  const u16* Qh = Qb + (size_t)bh * 2048 * 64;
  const u16* Kh = Kb + (size_t)bh * 2048 * 64;
  const u16* Vh = VTb + (size_t)bh * 64 * 2048;

  const int q0 = qt * 64;
  const int qfrag = q0 + w * 16 + lo;  // A-operand row for this lane
  const bf16x8 qa0 = *reinterpret_cast<const bf16x8*>(Qh + (size_t)qfrag * 64 + hi * 8);
  const bf16x8 qa1 = *reinterpret_cast<const bf16x8*>(Qh + (size_t)qfrag * 64 + 32 + hi * 8);

  float mrun[4], lrun[4];
  floatx4 accv[4];  // [d-ntile][r]
  for (int r = 0; r < 4; ++r) { mrun[r] = -3.0e38f; lrun[r] = 0.f; }
  for (int dt = 0; dt < 4; ++dt) accv[dt] = (floatx4)0.f;

  const int qbase = q0 + w * 16 + hi * 4;  // +r = this lane's C-layout rows
  const int kt0 = (qt == 31) ? 0 : qt;     // anti-causal skip; full sweep for last tile

  for (int kt = kt0; kt < 32; ++kt) {
    const int k0 = kt * 64;
    {  // stage K tile (contiguous 8KB) and V^T tile (64 rows x 128B)
      const u16* gK = Kh + (size_t)k0 * 64;
      for (int j = 0; j < 2; ++j) {
        const int seg = w * 2 + j;  // 0..7, 1KB each
        glds16(Ks + seg * 512, gK + seg * 512 + lane * 8);
        const int row = seg * 8 + (lane >> 3);
        glds16(Vs + seg * 512, Vh + (size_t)row * 2048 + k0 + (lane & 7) * 8);
      }
    }
    __syncthreads();

    // S = Q K^T  (16 q-rows x 64 keys per wave)
    floatx4 sc[4];
    for (int nt = 0; nt < 4; ++nt) sc[nt] = (floatx4)0.f;
    for (int nt = 0; nt < 4; ++nt) {
      bf16x8 kb = *reinterpret_cast<const bf16x8*>(Ks + (nt * 16 + lo) * 64 + hi * 8);
      sc[nt] = MFMA16(qa0, kb, sc[nt]);
    }
    for (int nt = 0; nt < 4; ++nt) {
      bf16x8 kb = *reinterpret_cast<const bf16x8*>(Ks + (nt * 16 + lo) * 64 + 32 + hi * 8);
      sc[nt] = MFMA16(qa1, kb, sc[nt]);
    }

    // scale + faithful mask (exact -1e9 like the reference masked_fill)
    float sv[4][4];
    for (int nt = 0; nt < 4; ++nt) {
      const int key = k0 + nt * 16 + lo;
      for (int r = 0; r < 4; ++r)
        sv[nt][r] = (key > qbase + r) ? sc[nt][r] * 0.25f : -1000000000.0f;
    }

    // online softmax (row stats replicated across each 16-lane group)
    float al[4];
    for (int r = 0; r < 4; ++r) {
      float mx = fmaxf(fmaxf(sv[0][r], sv[1][r]), fmaxf(sv[2][r], sv[3][r]));
      for (int off = 1; off < 16; off <<= 1) mx = fmaxf(mx, __shfl_xor(mx, off));
      const float mnew = fmaxf(mrun[r], mx);
      al[r] = __expf(mrun[r] - mnew);
      mrun[r] = mnew;
    }
    float rs[4] = {0.f, 0.f, 0.f, 0.f};
    for (int nt = 0; nt < 4; ++nt)
      for (int r = 0; r < 4; ++r) {
        const float p = __expf(sv[nt][r] - mrun[r]);
        rs[r] += p;
        Ps[w][(hi * 4 + r) * 64 + nt * 16 + lo] = f2bf(p);  // C-layout -> row-major
      }
    for (int r = 0; r < 4; ++r) {
      float s = rs[r];
      for (int off = 1; off < 16; off <<= 1) s += __shfl_xor(s, off);
      lrun[r] = lrun[r] * al[r] + s;
    }
    for (int dt = 0; dt < 4; ++dt)
      for (int r = 0; r < 4; ++r) accv[dt][r] *= al[r];

    // O += P V   (P from LDS in A-layout; V^T rows are the B operand)
    for (int kk = 0; kk < 2; ++kk) {
      bf16x8 pa = *reinterpret_cast<const bf16x8*>(&Ps[w][lo * 64 + kk * 32 + hi * 8]);
      for (int dt = 0; dt < 4; ++dt) {
        bf16x8 vb = *reinterpret_cast<const bf16x8*>(Vs + (dt * 16 + lo) * 64 + kk * 32 + hi * 8);
        accv[dt] = MFMA16(pa, vb, accv[dt]);
      }
    }
    __syncthreads();
  }

  const int b = bh >> 4, h = bh & 15;
  for (int dt = 0; dt < 4; ++dt)
    for (int r = 0; r < 4; ++r) {
      const int q = qbase + r;
      out[((size_t)(b * 2048 + q)) * 1024 + h * 64 + dt * 16 + lo] = accv[dt][r] / lrun[r];
    }
}

// ---------------------------------------------------------------- launch
extern "C" void kernel_launch(void* const* d_in, const int* in_sizes, int n_in,
                              void* d_out, int out_size, void* d_ws, size_t ws_size,
                              hipStream_t stream) {
  const float* x  = (const float*)d_in[0];
  const float* Wq = (const float*)d_in[1];
  const float* bq = (const float*)d_in[2];
  const float* Wk = (const float*)d_in[3];
  const float* bk = (const float*)d_in[4];
  const float* Wv = (const float*)d_in[5];
  const float* bv = (const float*)d_in[6];
  float* out = (float*)d_out;

  char* ws = (char*)d_ws;
  u16* xb  = (u16*)(ws);                  // 8 MB: x as bf16 [4096][1024]
  u16* Wb  = (u16*)(ws + (8u << 20));     // 6 MB: Wq,Wk,Wv bf16 [3][1024][1024]
  u16* Qb  = (u16*)(ws + (14u << 20));    // 8 MB: Q  [B,H,S,dh]
  u16* Kb  = (u16*)(ws + (22u << 20));    // 8 MB: K  [B,H,S,dh]
  u16* VTb = (u16*)(ws + (30u << 20));    // 8 MB: V^T [B,H,dh,S]  (ends 38 MB)

  cvt_bf16<<<4096, 256, 0, stream>>>(x, xb, 1048576);
  cvt_bf16<<<1024, 256, 0, stream>>>(Wq, Wb, 262144);
  cvt_bf16<<<1024, 256, 0, stream>>>(Wk, Wb + (1u << 20), 262144);
  cvt_bf16<<<1024, 256, 0, stream>>>(Wv, Wb + (2u << 20), 262144);

  qkv_gemm<<<dim3(8, 32, 3), 256, 0, stream>>>(xb, Wb, bq, bk, bv, Qb, Kb, VTb);
  attn<<<dim3(32, 32), 256, 0, stream>>>(Qb, Kb, VTb, out);
}

// Round 2
// 191.000 us; speedup vs baseline: 1.4089x; 1.4089x over previous
//
#include <hip/hip_runtime.h>
#include <stdint.h>

typedef unsigned short u16;
typedef __attribute__((ext_vector_type(8))) short bf16x8;   // 8 bf16 in 4 VGPRs
typedef __attribute__((ext_vector_type(4))) float floatx4;

#define MFMA16(a, b, c) __builtin_amdgcn_mfma_f32_16x16x32_bf16(a, b, c, 0, 0, 0)

__device__ __forceinline__ u16 f2bf(float f) {
  union { float f; unsigned u; } v; v.f = f;
  unsigned r = (v.u + 0x7FFFu + ((v.u >> 16) & 1u)) >> 16;
  return (u16)r;
}

// async global->LDS, 16B per lane. LDS dest = wave-uniform base + lane*16 (HW).
__device__ __forceinline__ void glds16(void* lds, const void* g) {
  __builtin_amdgcn_global_load_lds((const __attribute__((address_space(1))) void*)g,
                                   (__attribute__((address_space(3))) void*)lds,
                                   16, 0, 0);
}

// ---------------------------------------------------------------- convert
__global__ __launch_bounds__(256) void cvt_bf16(const float* __restrict__ src,
                                                u16* __restrict__ dst, int n4) {
  int i = blockIdx.x * 256 + threadIdx.x;
  if (i >= n4) return;
  float4 f = reinterpret_cast<const float4*>(src)[i];
  ushort4 o;
  o.x = f2bf(f.x); o.y = f2bf(f.y); o.z = f2bf(f.z); o.w = f2bf(f.w);
  reinterpret_cast<ushort4*>(dst)[i] = o;
}

// ---------------------------------------------------------------- QKV GEMM
// C[m,n] = sum_k x[m,k] * W[n,k] + bias[n]   (x @ W^T + b), M=4096 N=1024 K=1024
// which=0 -> Q [B,H,S,dh], which=1 -> K [B,H,S,dh], which=2 -> V^T [B,H,dh,S]
__global__ __launch_bounds__(256, 2) void qkv_gemm(
    const u16* __restrict__ xb, const u16* __restrict__ Wb,
    const float* __restrict__ bq, const float* __restrict__ bk,
    const float* __restrict__ bv,
    u16* __restrict__ Qb, u16* __restrict__ Kb, u16* __restrict__ VTb) {
  __shared__ __attribute__((aligned(16))) u16 As[128 * 64];
  __shared__ __attribute__((aligned(16))) u16 Bs[128 * 64];

  const int tid = threadIdx.x;
  const int w = tid >> 6, lane = tid & 63;
  const int lo = lane & 15, hi = lane >> 4;
  const int which = blockIdx.z;
  const int n0 = blockIdx.x * 128, m0 = blockIdx.y * 128;

  const u16* W = Wb + (size_t)which * (1024 * 1024);
  const int wm = (w >> 1) * 64, wn = (w & 1) * 64;

  floatx4 acc[4][4];
  for (int i = 0; i < 4; ++i)
    for (int j = 0; j < 4; ++j) acc[i][j] = (floatx4)0.f;

  const int arow = lane >> 3;        // 0..7 within 8-row segment
  const int acol = (lane & 7) * 8;   // bf16 element offset within 64

  for (int kt = 0; kt < 16; ++kt) {
    const int k0 = kt * 64;
    for (int j = 0; j < 4; ++j) {
      const int seg = w * 4 + j;          // 16 segs of 8 rows
      const int row = seg * 8 + arow;
      glds16(As + seg * 512, xb + (size_t)(m0 + row) * 1024 + k0 + acol);
      glds16(Bs + seg * 512, W + (size_t)(n0 + row) * 1024 + k0 + acol);
    }
    __syncthreads();
    for (int kk = 0; kk < 2; ++kk) {
      bf16x8 af[4], bfr[4];
      for (int it = 0; it < 4; ++it)
        af[it] = *reinterpret_cast<const bf16x8*>(As + (wm + it * 16 + lo) * 64 + kk * 32 + hi * 8);
      for (int jt = 0; jt < 4; ++jt)
        bfr[jt] = *reinterpret_cast<const bf16x8*>(Bs + (wn + jt * 16 + lo) * 64 + kk * 32 + hi * 8);
      for (int it = 0; it < 4; ++it)
        for (int jt = 0; jt < 4; ++jt)
          acc[it][jt] = MFMA16(af[it], bfr[jt], acc[it][jt]);
    }
    __syncthreads();
  }

  const float* bias = (which == 0) ? bq : (which == 1) ? bk : bv;
  for (int it = 0; it < 4; ++it) {
    const int mrow = m0 + wm + it * 16 + hi * 4;  // +r ; multiple of 4, no batch straddle
    const int b = mrow >> 11;
    const int s = mrow & 2047;
    for (int jt = 0; jt < 4; ++jt) {
      const int ncol = n0 + wn + jt * 16 + lo;
      const int h = ncol >> 6, d = ncol & 63;
      const float bb = bias[ncol];
      if (which == 2) {
        ushort4 o;
        o.x = f2bf(acc[it][jt][0] + bb);
        o.y = f2bf(acc[it][jt][1] + bb);
        o.z = f2bf(acc[it][jt][2] + bb);
        o.w = f2bf(acc[it][jt][3] + bb);
        *reinterpret_cast<ushort4*>(VTb + ((size_t)(b * 16 + h) * 64 + d) * 2048 + s) = o;
      } else {
        u16* dst = ((which == 0) ? Qb : Kb) + ((size_t)(b * 16 + h) * 2048 + s) * 64 + d;
        for (int r = 0; r < 4; ++r)
          dst[(size_t)r * 64] = f2bf(acc[it][jt][r] + bb);
      }
    }
  }
}

// ---------------------------------------------------------------- attention
// Transposed formulation: S^T = K*Q^T (lane owns one q-row), O^T = V^T*P^T.
// Faithful buggy mask: keep score iff key > q, else -1e9 (row S-1 -> uniform).
// Block = 512 thr / 8 waves: waves 0-3 do q-tile qtA, waves 4-7 do qtB,
// sharing K/V staging. Pairing {i,30-i}; block 15 = {15,31} (qt31 needs the
// full k-sweep because its last row is fully masked -> uniform over all keys).
__global__ __launch_bounds__(512, 4) void attn(
    const u16* __restrict__ Qb, const u16* __restrict__ Kb,
    const u16* __restrict__ VTb, float* __restrict__ out) {
  __shared__ __attribute__((aligned(16))) u16 Ks[64 * 64];    // [key][d] swizzled
  __shared__ __attribute__((aligned(16))) u16 Vs[64 * 64];    // [d][key] swizzled
  __shared__ __attribute__((aligned(16))) u16 Pt[8][16 * 72]; // per-wave P [q][key] pad72

  const int pair = blockIdx.x, bh = blockIdx.y;
  const int tid = threadIdx.x, w = tid >> 6, lane = tid & 63;
  const int lo = lane & 15, quad = lane >> 4;

  const int qtA = pair;
  const int qtB = (pair == 15) ? 31 : 30 - pair;
  const int g = w >> 2, wl = w & 3;
  const int qt = g ? qtB : qtA;
  const int kstart = (pair == 15) ? 0 : pair;
  const int kact = (qt == 31) ? 0 : qt;

  const u16* Qh = Qb + (size_t)bh * 2048 * 64;
  const u16* Kh = Kb + (size_t)bh * 2048 * 64;
  const u16* Vh = VTb + (size_t)bh * 64 * 2048;

  const int qrow = qt * 64 + wl * 16 + lo;     // lane's q (MFMA n-index)
  const bf16x8 qb0 = *reinterpret_cast<const bf16x8*>(Qh + (size_t)qrow * 64 + quad * 8);
  const bf16x8 qb1 = *reinterpret_cast<const bf16x8*>(Qh + (size_t)qrow * 64 + 32 + quad * 8);

  float mrun = -3.0e38f, lrun = 0.f;
  floatx4 acc[4];   // O^T C-layout: col=lo=q, row=quad*4+r = d within dt*16
  for (int dt = 0; dt < 4; ++dt) acc[dt] = (floatx4)0.f;

  u16* ptw = &Pt[w][0];
  const int r8 = lane >> 3, b8 = lane & 7;
  const int srow = w * 8 + r8;                 // staging row for this lane
  const int scb = (b8 ^ (srow & 7)) * 8;       // XOR-swizzled global col block

  for (int kt = kstart; kt < 32; ++kt) {
    const int k0 = kt * 64;
    glds16(Ks + w * 512, Kh + (size_t)(k0 + srow) * 64 + scb);
    glds16(Vs + w * 512, Vh + (size_t)srow * 2048 + k0 + scb);
    __syncthreads();

    if (kt >= kact) {
      // S^T = K·Q^T : A = K frag (m=key, 4 tiles), B = Q frag (n=q)
      floatx4 sc[4];
      for (int t = 0; t < 4; ++t) sc[t] = (floatx4)0.f;
      for (int t = 0; t < 4; ++t) {
        bf16x8 ka = *reinterpret_cast<const bf16x8*>(
            Ks + (t * 16 + lo) * 64 + ((quad ^ (lo & 7)) * 8));
        sc[t] = MFMA16(ka, qb0, sc[t]);
      }
      for (int t = 0; t < 4; ++t) {
        bf16x8 ka = *reinterpret_cast<const bf16x8*>(
            Ks + (t * 16 + lo) * 64 + (((4 + quad) ^ (lo & 7)) * 8));
        sc[t] = MFMA16(ka, qb1, sc[t]);
      }

      // mask + scale; lane owns q=qrow, keys = k0 + t*16 + quad*4 + r
      float sv[4][4];
      float mx = -3.0e38f;
      for (int t = 0; t < 4; ++t)
        for (int r = 0; r < 4; ++r) {
          const int key = k0 + t * 16 + quad * 4 + r;
          const float v = (key > qrow) ? sc[t][r] * 0.25f : -1000000000.0f;
          sv[t][r] = v;
          mx = fmaxf(mx, v);
        }
      mx = fmaxf(mx, __shfl_xor(mx, 16));
      mx = fmaxf(mx, __shfl_xor(mx, 32));
      const float mnew = fmaxf(mrun, mx);
      const float al = __expf(mrun - mnew);
      mrun = mnew;

      float rs = 0.f;
      for (int t = 0; t < 4; ++t) {
        const float p0 = __expf(sv[t][0] - mnew);
        const float p1 = __expf(sv[t][1] - mnew);
        const float p2 = __expf(sv[t][2] - mnew);
        const float p3 = __expf(sv[t][3] - mnew);
        rs += (p0 + p1) + (p2 + p3);
        ushort4 pk;
        pk.x = f2bf(p0); pk.y = f2bf(p1); pk.z = f2bf(p2); pk.w = f2bf(p3);
        *reinterpret_cast<ushort4*>(ptw + lo * 72 + t * 16 + quad * 4) = pk;
      }
      rs += __shfl_xor(rs, 16);
      rs += __shfl_xor(rs, 32);
      lrun = lrun * al + rs;
      for (int dt = 0; dt < 4; ++dt) acc[dt] *= al;

      // O^T += V^T·P^T : A = V^T frag (m=d), B = P frag (n=q) from per-wave LDS
      for (int kk = 0; kk < 2; ++kk) {
        bf16x8 pb = *reinterpret_cast<const bf16x8*>(ptw + lo * 72 + kk * 32 + quad * 8);
        for (int dt = 0; dt < 4; ++dt) {
          bf16x8 va = *reinterpret_cast<const bf16x8*>(
              Vs + (dt * 16 + lo) * 64 + (((kk * 4 + quad) ^ (lo & 7)) * 8));
          acc[dt] = MFMA16(va, pb, acc[dt]);
        }
      }
    }
    __syncthreads();
  }

  const float rl = 1.f / lrun;
  const int b = bh >> 4, h = bh & 15;
  float* op = out + ((size_t)(b * 2048 + qrow)) * 1024 + h * 64 + quad * 4;
  for (int dt = 0; dt < 4; ++dt) {
    float4 o4;
    o4.x = acc[dt][0] * rl; o4.y = acc[dt][1] * rl;
    o4.z = acc[dt][2] * rl; o4.w = acc[dt][3] * rl;
    *reinterpret_cast<float4*>(op + dt * 16) = o4;
  }
}

// ---------------------------------------------------------------- launch
extern "C" void kernel_launch(void* const* d_in, const int* in_sizes, int n_in,
                              void* d_out, int out_size, void* d_ws, size_t ws_size,
                              hipStream_t stream) {
  const float* x  = (const float*)d_in[0];
  const float* Wq = (const float*)d_in[1];
  const float* bq = (const float*)d_in[2];
  const float* Wk = (const float*)d_in[3];
  const float* bk = (const float*)d_in[4];
  const float* Wv = (const float*)d_in[5];
  const float* bv = (const float*)d_in[6];
  float* out = (float*)d_out;

  char* ws = (char*)d_ws;
  u16* xb  = (u16*)(ws);                  // 8 MB: x as bf16 [4096][1024]
  u16* Wb  = (u16*)(ws + (8u << 20));     // 6 MB: Wq,Wk,Wv bf16 [3][1024][1024]
  u16* Qb  = (u16*)(ws + (14u << 20));    // 8 MB: Q  [B,H,S,dh]
  u16* Kb  = (u16*)(ws + (22u << 20));    // 8 MB: K  [B,H,S,dh]
  u16* VTb = (u16*)(ws + (30u << 20));    // 8 MB: V^T [B,H,dh,S]  (ends 38 MB)

  cvt_bf16<<<4096, 256, 0, stream>>>(x, xb, 1048576);
  cvt_bf16<<<1024, 256, 0, stream>>>(Wq, Wb, 262144);
  cvt_bf16<<<1024, 256, 0, stream>>>(Wk, Wb + (1u << 20), 262144);
  cvt_bf16<<<1024, 256, 0, stream>>>(Wv, Wb + (2u << 20), 262144);

  qkv_gemm<<<dim3(8, 32, 3), 256, 0, stream>>>(xb, Wb, bq, bk, bv, Qb, Kb, VTb);
  attn<<<dim3(16, 32), 512, 0, stream>>>(Qb, Kb, VTb, out);
}

// Round 3
// 177.610 us; speedup vs baseline: 1.5151x; 1.0754x over previous
//
#include <hip/hip_runtime.h>
#include <stdint.h>

typedef unsigned short u16;
typedef __attribute__((ext_vector_type(8))) short bf16x8;   // 8 bf16 in 4 VGPRs
typedef __attribute__((ext_vector_type(4))) float floatx4;

#define MFMA16(a, b, c) __builtin_amdgcn_mfma_f32_16x16x32_bf16(a, b, c, 0, 0, 0)
#define MASKV (-1.4426950408889634e9f)   /* -1e9 * log2(e): mask in exp2 domain */

#if __has_builtin(__builtin_amdgcn_exp2f)
#define EXP2(x) __builtin_amdgcn_exp2f(x)
#else
#define EXP2(x) __expf(0.6931471805599453f * (x))
#endif

__device__ __forceinline__ u16 f2bf(float f) {   // round-to-nearest-even
  unsigned u = __builtin_bit_cast(unsigned, f);
  return (u16)((u + 0x7FFFu + ((u >> 16) & 1u)) >> 16);
}
__device__ __forceinline__ unsigned pkbf(float a, float b) {  // round-half-up pack
  unsigned ua = __builtin_bit_cast(unsigned, a);
  unsigned ub = __builtin_bit_cast(unsigned, b);
  return ((ua + 0x8000u) >> 16) | ((ub + 0x8000u) & 0xFFFF0000u);
}

// async global->LDS, 16B/lane. LDS dest = wave-uniform base + lane*16 (HW).
__device__ __forceinline__ void glds16(void* lds, const void* g) {
  __builtin_amdgcn_global_load_lds((const __attribute__((address_space(1))) void*)g,
                                   (__attribute__((address_space(3))) void*)lds,
                                   16, 0, 0);
}

// ---------------------------------------------------------------- convert
__global__ __launch_bounds__(256) void cvt_bf16(const float* __restrict__ src,
                                                u16* __restrict__ dst, int n4) {
  int i = blockIdx.x * 256 + threadIdx.x;
  if (i >= n4) return;
  float4 f = reinterpret_cast<const float4*>(src)[i];
  ushort4 o;
  o.x = f2bf(f.x); o.y = f2bf(f.y); o.z = f2bf(f.z); o.w = f2bf(f.w);
  reinterpret_cast<ushort4*>(dst)[i] = o;
}
// one launch converts all three 1024x1024 weight matrices (blockIdx.z picks)
__global__ __launch_bounds__(256) void cvt_w3(const float* __restrict__ w0,
                                              const float* __restrict__ w1,
                                              const float* __restrict__ w2,
                                              u16* __restrict__ dst) {
  const float* src = (blockIdx.z == 0) ? w0 : (blockIdx.z == 1) ? w1 : w2;
  u16* d = dst + (size_t)blockIdx.z * (1024 * 1024);
  int i = blockIdx.x * 256 + threadIdx.x;   // 262144 float4 groups
  float4 f = reinterpret_cast<const float4*>(src)[i];
  ushort4 o;
  o.x = f2bf(f.x); o.y = f2bf(f.y); o.z = f2bf(f.z); o.w = f2bf(f.w);
  reinterpret_cast<ushort4*>(d)[i] = o;
}

// ---------------------------------------------------------------- QKV GEMM
// C[m,n] = sum_k x[m,k]*W[n,k] + bias[n]; M=4096 N=1024 K=1024.
// which=0 -> Q [B,H,S,dh] (pre-scaled by 0.25*log2e), 1 -> K [B,H,S,dh],
// 2 -> V^T [B,H,dh,S]. Epilogue goes through an LDS transpose so every
// global store is a wide coalesced dwordx4 (the R2 scatter stores were the
// gemm bottleneck).
__global__ __launch_bounds__(256, 2) void qkv_gemm(
    const u16* __restrict__ xb, const u16* __restrict__ Wb,
    const float* __restrict__ bq, const float* __restrict__ bk,
    const float* __restrict__ bv,
    u16* __restrict__ Qb, u16* __restrict__ Kb, u16* __restrict__ VTb) {
  __shared__ __attribute__((aligned(16))) u16 smem[2 * 128 * 64];
  u16* As = smem;
  u16* Bs = smem + 128 * 64;

  const int tid = threadIdx.x;
  const int w = tid >> 6, lane = tid & 63;
  const int lo = lane & 15, quad = lane >> 4;
  const int which = blockIdx.z;
  const int n0 = blockIdx.x * 128, m0 = blockIdx.y * 128;

  const u16* W = Wb + (size_t)which * (1024 * 1024);
  const int wm = (w >> 1) * 64, wn = (w & 1) * 64;

  floatx4 acc[4][4];
  for (int i = 0; i < 4; ++i)
    for (int j = 0; j < 4; ++j) acc[i][j] = (floatx4)0.f;

  const int arow = lane >> 3;        // 0..7 within 8-row segment
  const int acol = (lane & 7) * 8;   // bf16 element offset within 64

  for (int kt = 0; kt < 16; ++kt) {
    const int k0 = kt * 64;
    for (int j = 0; j < 4; ++j) {
      const int seg = w * 4 + j;          // 16 segs of 8 rows
      const int row = seg * 8 + arow;
      glds16(As + seg * 512, xb + (size_t)(m0 + row) * 1024 + k0 + acol);
      glds16(Bs + seg * 512, W + (size_t)(n0 + row) * 1024 + k0 + acol);
    }
    __syncthreads();
    for (int kk = 0; kk < 2; ++kk) {
      bf16x8 af[4], bfr[4];
      for (int it = 0; it < 4; ++it)
        af[it] = *reinterpret_cast<const bf16x8*>(As + (wm + it * 16 + lo) * 64 + kk * 32 + quad * 8);
      for (int jt = 0; jt < 4; ++jt)
        bfr[jt] = *reinterpret_cast<const bf16x8*>(Bs + (wn + jt * 16 + lo) * 64 + kk * 32 + quad * 8);
      for (int it = 0; it < 4; ++it)
        for (int jt = 0; jt < 4; ++jt)
          acc[it][jt] = MFMA16(af[it], bfr[jt], acc[it][jt]);
    }
    __syncthreads();   // also guarantees smem reusable for the epilogue
  }

  const float* bias = (which == 0) ? bq : (which == 1) ? bk : bv;
  float bb[4];
  for (int jt = 0; jt < 4; ++jt) bb[jt] = bias[n0 + wn + jt * 16 + lo];
  const int b = m0 >> 11;

  if (which < 2) {
    // per-wave 16x64 transpose tiles; rows=s(16), cols=d(64), pad->72
    const float scl = (which == 0) ? 0.36067376022224085f : 1.0f;  // 0.25*log2e
    u16* Tw = smem + w * (16 * 72);
    const int hblk = (n0 + wn) >> 6;
    u16* dst = ((which == 0) ? Qb : Kb) +
               ((size_t)(b * 16 + hblk) * 2048 + ((m0 & 2047) + wm)) * 64;
    for (int it = 0; it < 4; ++it) {
      for (int jt = 0; jt < 4; ++jt)
        for (int r = 0; r < 4; ++r) {
          const int m = quad * 4 + r, col = jt * 16 + lo;
          Tw[m * 72 + (((col >> 3) ^ (m & 7)) * 8) + (col & 7)] =
              f2bf((acc[it][jt][r] + bb[jt]) * scl);
        }
      for (int rd = 0; rd < 2; ++rd) {   // per-wave, in-order DS: no barrier
        const int sr = rd * 8 + (lane >> 3), d8 = lane & 7;
        bf16x8 v = *reinterpret_cast<const bf16x8*>(Tw + sr * 72 + ((d8 ^ (sr & 7)) * 8));
        *reinterpret_cast<bf16x8*>(dst + (size_t)(it * 16 + sr) * 64 + d8 * 8) = v;
      }
    }
  } else {
    // V^T: block transpose [128 n][64 m] (pad->72) in two m-passes,
    // read back as full 128B s-rows.
    for (int pass = 0; pass < 2; ++pass) {
      if ((wm >> 6) == pass) {
        for (int it = 0; it < 4; ++it)
          for (int jt = 0; jt < 4; ++jt)
            for (int r = 0; r < 4; ++r) {
              const int n = wn + jt * 16 + lo;
              const int m = it * 16 + quad * 4 + r;   // local 0..63
              smem[n * 72 + (((m >> 3) ^ (n & 7)) * 8) + (m & 7)] =
                  f2bf(acc[it][jt][r] + bb[jt]);
            }
      }
      __syncthreads();
      for (int rd = 0; rd < 4; ++rd) {
        const int n = (tid >> 3) + rd * 32, m8 = tid & 7;
        bf16x8 v = *reinterpret_cast<const bf16x8*>(smem + n * 72 + ((m8 ^ (n & 7)) * 8));
        const int ng = n0 + n, h = ng >> 6, d = ng & 63;
        const int s = (m0 & 2047) + pass * 64 + m8 * 8;
        *reinterpret_cast<bf16x8*>(VTb + ((size_t)(b * 16 + h) * 64 + d) * 2048 + s) = v;
      }
      __syncthreads();
    }
  }
}

// ---------------------------------------------------------------- attention
// Transposed flash: S^T = K*Q^T (lane owns one q-row), O^T = V^T*P^T.
// Q pre-scaled by 0.25*log2e -> probs = exp2(s' - m'). Faithful buggy mask
// keeps key > q (masked -> -1e9, i.e. MASKV in exp2 domain; row 2047 ->
// uniform over all 2048 keys).
// 256 thr / 4 waves, one q-tile per block; double-buffered K/V staging with
// prefetch issued before compute so the barrier's vmcnt drain overlaps MFMA.
__global__ __launch_bounds__(256, 3) void attn(
    const u16* __restrict__ Qb, const u16* __restrict__ Kb,
    const u16* __restrict__ VTb, float* __restrict__ out) {
  __shared__ __attribute__((aligned(16))) u16 Ks[2][64 * 64];   // [key][d] swizzled
  __shared__ __attribute__((aligned(16))) u16 Vs[2][64 * 64];   // [d][key] swizzled
  __shared__ __attribute__((aligned(16))) u16 Pt[4][16 * 72];   // per-wave P [q][key]

  // XCD-aware swizzle (same-bh blocks share an XCD's L2) + LPT order
  const int L = blockIdx.x;
  const int xcd = L & 7, slot = L >> 3;
  const int bh = xcd + 8 * (slot >> 5);
  const int s5 = slot & 31;
  const int qt = (s5 == 0) ? 0 : (s5 == 1) ? 31 : (s5 - 1);  // longest first

  const int tid = threadIdx.x, w = tid >> 6, lane = tid & 63;
  const int lo = lane & 15, quad = lane >> 4;

  const u16* Qh = Qb + (size_t)bh * (2048 * 64);
  const u16* Kh = Kb + (size_t)bh * (2048 * 64);
  const u16* Vh = VTb + (size_t)bh * (64 * 2048);

  const int qrow = qt * 64 + w * 16 + lo;
  const bf16x8 qb0 = *reinterpret_cast<const bf16x8*>(Qh + (size_t)qrow * 64 + quad * 8);
  const bf16x8 qb1 = *reinterpret_cast<const bf16x8*>(Qh + (size_t)qrow * 64 + 32 + quad * 8);

  float mrun = -3.0e38f, lrun = 0.f;
  floatx4 acc[4];
  for (int dt = 0; dt < 4; ++dt) acc[dt] = (floatx4)0.f;

  u16* ptw = &Pt[w][0];
  const int srow8 = lane >> 3, sblk = lane & 7;
  const int sswz = (sblk ^ srow8) * 8;      // XOR swizzle, row&7 == srow8

  const int kstart = (qt == 31) ? 0 : qt;

  if (qt == 31) {  // constant P=1 for the 31 fully-masked tiles
    bf16x8 ones;
    for (int i = 0; i < 8; ++i) ones[i] = (short)0x3F80;
    *reinterpret_cast<bf16x8*>(ptw + lo * 72 + quad * 16) = ones;
    *reinterpret_cast<bf16x8*>(ptw + lo * 72 + quad * 16 + 8) = ones;
  }

  // prologue stage into buf 0
  {
    const int kt = kstart;
    if (qt != 31 || kt == 31)
      for (int j = 0; j < 2; ++j) {
        const int b8 = (w * 2 + j) * 8;
        glds16(&Ks[0][b8 * 64], Kh + (size_t)(kt * 64 + b8 + srow8) * 64 + sswz);
      }
    for (int j = 0; j < 2; ++j) {
      const int b8 = (w * 2 + j) * 8;
      glds16(&Vs[0][b8 * 64], Vh + (size_t)(b8 + srow8) * 2048 + kt * 64 + sswz);
    }
  }
  __syncthreads();

  for (int kt = kstart; kt < 32; ++kt) {
    const int cur = (kt - kstart) & 1, nxt = cur ^ 1;
    if (kt < 31) {  // prefetch next tile BEFORE compute (latency overlap)
      const int kn = kt + 1;
      if (qt != 31 || kn == 31)
        for (int j = 0; j < 2; ++j) {
          const int b8 = (w * 2 + j) * 8;
          glds16(&Ks[nxt][b8 * 64], Kh + (size_t)(kn * 64 + b8 + srow8) * 64 + sswz);
        }
      for (int j = 0; j < 2; ++j) {
        const int b8 = (w * 2 + j) * 8;
        glds16(&Vs[nxt][b8 * 64], Vh + (size_t)(b8 + srow8) * 2048 + kn * 64 + sswz);
      }
    }
    const u16* ksb = Ks[cur];
    const u16* vsb = Vs[cur];

    float al;
    if (qt == 31 && kt < 31) {
      // all scores == MASKV: p = 1, Pt already ones; skip QK entirely
      const float mnew = fmaxf(mrun, MASKV);
      al = EXP2(mrun - mnew);     // 0 on first tile, 1 after
      mrun = mnew;
      lrun = lrun * al + 64.f;
    } else {
      floatx4 sc[4];
      for (int t = 0; t < 4; ++t) sc[t] = (floatx4)0.f;
      const int swz0 = (quad ^ (lo & 7)) * 8;
      const int swz1 = ((quad + 4) ^ (lo & 7)) * 8;
      for (int t = 0; t < 4; ++t) {
        bf16x8 ka = *reinterpret_cast<const bf16x8*>(ksb + (t * 16 + lo) * 64 + swz0);
        sc[t] = MFMA16(ka, qb0, sc[t]);
      }
      for (int t = 0; t < 4; ++t) {
        bf16x8 ka = *reinterpret_cast<const bf16x8*>(ksb + (t * 16 + lo) * 64 + swz1);
        sc[t] = MFMA16(ka, qb1, sc[t]);
      }

      bool zt[4] = {false, false, false, false};
      float mx = -3.0e38f;
      if (kt == qt) {   // the only tile with masking (subtile-classified by w)
        const int k0 = kt * 64;
        for (int t = 0; t < 4; ++t) {
          zt[t] = (qt != 31) && (t < w);   // wholly-masked & a real key follows
          if (zt[t]) continue;
          if (t <= w) {                    // needs per-key mask
            for (int r = 0; r < 4; ++r) {
              const int key = k0 + t * 16 + quad * 4 + r;
              sc[t][r] = (key > qrow) ? sc[t][r] : MASKV;
            }
          }
          mx = fmaxf(mx, fmaxf(fmaxf(sc[t][0], sc[t][1]), fmaxf(sc[t][2], sc[t][3])));
        }
      } else {          // clean fast path: kt > qt -> nothing masked
        for (int t = 0; t < 4; ++t)
          mx = fmaxf(mx, fmaxf(fmaxf(sc[t][0], sc[t][1]), fmaxf(sc[t][2], sc[t][3])));
      }
      mx = fmaxf(mx, __shfl_xor(mx, 16));
      mx = fmaxf(mx, __shfl_xor(mx, 32));
      const float mnew = fmaxf(mrun, mx);
      al = EXP2(mrun - mnew);
      mrun = mnew;

      float rs = 0.f;
      for (int t = 0; t < 4; ++t) {
        u16* pdst = ptw + lo * 72 + t * 16 + quad * 4;
        if (zt[t]) { *reinterpret_cast<uint2*>(pdst) = make_uint2(0u, 0u); continue; }
        const float p0 = EXP2(sc[t][0] - mnew), p1 = EXP2(sc[t][1] - mnew);
        const float p2 = EXP2(sc[t][2] - mnew), p3 = EXP2(sc[t][3] - mnew);
        rs += (p0 + p1) + (p2 + p3);
        *reinterpret_cast<uint2*>(pdst) = make_uint2(pkbf(p0, p1), pkbf(p2, p3));
      }
      rs += __shfl_xor(rs, 16);
      rs += __shfl_xor(rs, 32);
      lrun = lrun * al + rs;
    }
    for (int dt = 0; dt < 4; ++dt) acc[dt] *= al;

    // O^T += V^T * P^T
    for (int kk = 0; kk < 2; ++kk) {
      bf16x8 pb = *reinterpret_cast<const bf16x8*>(ptw + lo * 72 + kk * 32 + quad * 8);
      for (int dt = 0; dt < 4; ++dt) {
        bf16x8 va = *reinterpret_cast<const bf16x8*>(
            vsb + (dt * 16 + lo) * 64 + (((kk * 4 + quad) ^ (lo & 7)) * 8));
        acc[dt] = MFMA16(va, pb, acc[dt]);
      }
    }
    __syncthreads();   // next-tile staging complete + everyone done with cur
  }

  const float rl = 1.f / lrun;
  const int b = bh >> 4, h = bh & 15;
  float* op = out + ((size_t)(b * 2048 + qrow)) * 1024 + h * 64 + quad * 4;
  for (int dt = 0; dt < 4; ++dt) {
    float4 o4;
    o4.x = acc[dt][0] * rl; o4.y = acc[dt][1] * rl;
    o4.z = acc[dt][2] * rl; o4.w = acc[dt][3] * rl;
    *reinterpret_cast<float4*>(op + dt * 16) = o4;
  }
}

// ---------------------------------------------------------------- launch
extern "C" void kernel_launch(void* const* d_in, const int* in_sizes, int n_in,
                              void* d_out, int out_size, void* d_ws, size_t ws_size,
                              hipStream_t stream) {
  const float* x  = (const float*)d_in[0];
  const float* Wq = (const float*)d_in[1];
  const float* bq = (const float*)d_in[2];
  const float* Wk = (const float*)d_in[3];
  const float* bk = (const float*)d_in[4];
  const float* Wv = (const float*)d_in[5];
  const float* bv = (const float*)d_in[6];
  float* out = (float*)d_out;

  char* ws = (char*)d_ws;
  u16* xb  = (u16*)(ws);                  // 8 MB: x as bf16 [4096][1024]
  u16* Wb  = (u16*)(ws + (8u << 20));     // 6 MB: Wq,Wk,Wv bf16
  u16* Qb  = (u16*)(ws + (14u << 20));    // 8 MB: Q  [B,H,S,dh] (pre-scaled)
  u16* Kb  = (u16*)(ws + (22u << 20));    // 8 MB: K  [B,H,S,dh]
  u16* VTb = (u16*)(ws + (30u << 20));    // 8 MB: V^T [B,H,dh,S]

  cvt_bf16<<<4096, 256, 0, stream>>>(x, xb, 1048576);
  cvt_w3<<<dim3(1024, 1, 3), 256, 0, stream>>>(Wq, Wk, Wv, Wb);

  qkv_gemm<<<dim3(8, 32, 3), 256, 0, stream>>>(xb, Wb, bq, bk, bv, Qb, Kb, VTb);
  attn<<<dim3(1024), 256, 0, stream>>>(Qb, Kb, VTb, out);
}